// Round 2
// baseline (250.613 us; speedup 1.0000x reference)
//
#include <hip/hip_runtime.h>
#include <math.h>

#define NCLASS 1000
#define NCHUNK 250            // 1000 / 4 float4 chunks per row
#define RPW 4                 // rows per wave
#define WPB 4                 // waves per block
#define RPB (RPW * WPB)       // rows per block = 16

// Single fused kernel: per-block D-slice max + 16 rows of fused
// max/argmax + logsumexp + gather; last-done block folds the partials.
__global__ __launch_bounds__(256) void hce_fused(
    const float* __restrict__ y_pred,
    const int*   __restrict__ y_true,
    const float* __restrict__ D,
    float* __restrict__ partial,          // [0,nb): sums; [nb,2nb): maxes
    unsigned int* __restrict__ counter,   // zeroed via hipMemsetAsync
    float* __restrict__ out,
    int nb, int dsize, float invB)
{
    const int tid  = threadIdx.x;
    const int lane = tid & 63;
    const int wave = tid >> 6;
    const int b    = blockIdx.x;

    // ---- distance_matrix max over this block's slice ----
    float dm = -1.0f;                     // D is uniform[0,1): nonnegative
    for (int i = b * 256 + tid; i < dsize; i += nb * 256)
        dm = fmaxf(dm, D[i]);

    // ---- preload all 4 rows of this wave (MLP: 16 dwordx4 in flight) ----
    const int row0 = b * RPB + wave * RPW;
    float4 v[RPW][4];
    #pragma unroll
    for (int r = 0; r < RPW; ++r) {
        const float4* rp4 = (const float4*)(y_pred + (size_t)(row0 + r) * NCLASS);
        #pragma unroll
        for (int t = 0; t < 4; ++t) {
            int c = lane + 64 * t;
            if (c < NCHUNK) v[r][t] = rp4[c];
        }
    }
    const int nt = (lane < NCHUNK - 192) ? 4 : 3;   // lanes 0..57 own 4 chunks

    float acc = 0.0f;
    #pragma unroll
    for (int r = 0; r < RPW; ++r) {
        // phase 1: max + argmax (first occurrence = min col among ties)
        float m = -INFINITY; int arg = 0;
        #pragma unroll
        for (int t = 0; t < 4; ++t) {
            if (t < nt) {
                int col = 4 * (lane + 64 * t);
                if (v[r][t].x > m) { m = v[r][t].x; arg = col;     }
                if (v[r][t].y > m) { m = v[r][t].y; arg = col + 1; }
                if (v[r][t].z > m) { m = v[r][t].z; arg = col + 2; }
                if (v[r][t].w > m) { m = v[r][t].w; arg = col + 3; }
            }
        }
        #pragma unroll
        for (int off = 32; off; off >>= 1) {
            float om = __shfl_xor(m,   off, 64);
            int   oa = __shfl_xor(arg, off, 64);
            if (om > m || (om == m && oa < arg)) { m = om; arg = oa; }
        }

        // phase 2: sum of exp(x - m)
        float s = 0.0f;
        #pragma unroll
        for (int t = 0; t < 4; ++t) {
            if (t < nt) {
                s += __expf(v[r][t].x - m) + __expf(v[r][t].y - m)
                   + __expf(v[r][t].z - m) + __expf(v[r][t].w - m);
            }
        }
        #pragma unroll
        for (int off = 32; off; off >>= 1)
            s += __shfl_xor(s, off, 64);

        if (lane == 0) {
            int   tgt = y_true[row0 + r];
            float xt  = y_pred[(size_t)(row0 + r) * NCLASS + tgt];
            acc += (xt - m - __logf(s)) * D[arg * NCLASS + tgt];
        }
    }

    // ---- block-level combine ----
    #pragma unroll
    for (int off = 32; off; off >>= 1)
        dm = fmaxf(dm, __shfl_xor(dm, off, 64));

    __shared__ float ssum[WPB], smax[WPB];
    __shared__ int lastflag;
    if (lane == 0) { ssum[wave] = acc; smax[wave] = dm; }
    __syncthreads();

    if (tid == 0) {
        float bs = ssum[0] + ssum[1] + ssum[2] + ssum[3];
        float bm = fmaxf(fmaxf(smax[0], smax[1]), fmaxf(smax[2], smax[3]));
        __hip_atomic_store(&partial[b],      bs, __ATOMIC_RELAXED, __HIP_MEMORY_SCOPE_AGENT);
        __hip_atomic_store(&partial[nb + b], bm, __ATOMIC_RELAXED, __HIP_MEMORY_SCOPE_AGENT);
        unsigned prev = __hip_atomic_fetch_add(counter, 1u,
                            __ATOMIC_ACQ_REL, __HIP_MEMORY_SCOPE_AGENT);
        lastflag = (prev == (unsigned)(nb - 1));
    }
    __syncthreads();

    // ---- last-done block folds all partials ----
    if (lastflag) {
        float s = 0.0f, mx = -1.0f;
        for (int i = tid; i < nb; i += 256) {
            s  += __hip_atomic_load(&partial[i],      __ATOMIC_RELAXED, __HIP_MEMORY_SCOPE_AGENT);
            mx  = fmaxf(mx, __hip_atomic_load(&partial[nb + i],
                                              __ATOMIC_RELAXED, __HIP_MEMORY_SCOPE_AGENT));
        }
        #pragma unroll
        for (int off = 32; off; off >>= 1) {
            s  = s + __shfl_xor(s, off, 64);
            mx = fmaxf(mx, __shfl_xor(mx, off, 64));
        }
        if (lane == 0) { ssum[wave] = s; smax[wave] = mx; }
        __syncthreads();
        if (tid == 0) {
            float S = ssum[0] + ssum[1] + ssum[2] + ssum[3];
            float M = fmaxf(fmaxf(smax[0], smax[1]), fmaxf(smax[2], smax[3]));
            out[0] = -S * invB / M;
        }
    }
}

extern "C" void kernel_launch(void* const* d_in, const int* in_sizes, int n_in,
                              void* d_out, int out_size, void* d_ws, size_t ws_size,
                              hipStream_t stream) {
    const float* y_pred = (const float*)d_in[0];
    const int*   y_true = (const int*)  d_in[1];
    const float* D      = (const float*)d_in[2];
    // d_in[3] (fix_layer) is dead code in the reference.
    float* out = (float*)d_out;
    float* ws  = (float*)d_ws;

    const int B     = in_sizes[1];          // 32768
    const int dsize = in_sizes[2];          // 1000*1000
    const int nb    = B / RPB;              // 2048 blocks

    unsigned int* counter = (unsigned int*)(ws + 2 * (size_t)nb);
    hipMemsetAsync(counter, 0, sizeof(unsigned int), stream);
    hce_fused<<<nb, 256, 0, stream>>>(y_pred, y_true, D, ws, counter, out,
                                      nb, dsize, 1.0f / (float)B);
}